// Round 6
// baseline (4490.422 us; speedup 1.0000x reference)
//
#include <hip/hip_runtime.h>

// CustomLSTMClassifier on MI355X (gfx950) — round 6 (= round 5 resubmit)
// Persistent 128-block kernel, 512 sequential LSTM steps.
//  - fp16 weights/activations, fp32 accum + fp32 cell state in registers.
//  - Block owns 8 hidden units (32 gate cols f/i/o/g). Weight panel prepacked
//    in MFMA-fragment order, staged to LDS once (96 KB), reused 512 steps.
//  - h exchange: block's 64x8 h tile gathered in LDS -> 64 x 16B sc1 stores
//    (write-through to L3). Readers: per-step agent ACQUIRE fence (buffer_inv)
//    + plain CACHED dwordx4 loads -> 16 blocks/XCD share one L2 copy
//    (L3 traffic 16 MB/step -> 1 MB/step vs round 4's sc1 reads).
//  - barrier: per-step per-block flag words flag[t][bl]; tid0 sets flag after
//    wave0 drains h stores (flag doubles as intra-block release); ALL waves
//    poll with 2 coalesced sc1 loads/lane + ballot.
//  - x-GEMM for step t+1 overlaps the barrier wait for step t.

typedef _Float16 f16;
typedef _Float16 f16x8 __attribute__((ext_vector_type(8)));
typedef float f32x4 __attribute__((ext_vector_type(4)));
typedef unsigned short u16;
typedef unsigned int u32;

#define NBLK 128
#define SEQ 512

// workspace layout (bytes)
#define XH_OFF 0ull
#define XH_BYTES (64ull * 512 * 512 * 2)       // 33554432  x in fp16, [t][b][k]
#define WPRE_OFF (XH_OFF + XH_BYTES)
#define WPRE_BYTES (128ull * 48 * 2 * 64 * 16) // 12582912  per-block fragment-packed W
#define BIAS_OFF (WPRE_OFF + WPRE_BYTES)
#define BIAS_BYTES (128ull * 32 * 4)
#define HBUF_OFF (BIAS_OFF + BIAS_BYTES)
#define HBUF_BYTES (2ull * 32 * 64 * 4 * 16)   // 262144: dbuf h, frag order [kt][row][lq] x f16x8
#define HFIN_OFF (HBUF_OFF + HBUF_BYTES)
#define HFIN_BYTES (64ull * 1024 * 4)          // final h (fp32)
#define FLG_OFF (HFIN_OFF + HFIN_BYTES)
#define FLG_BYTES (512ull * 128 * 4)           // 262144: flag[t][bl]
#define WS_NEEDED (FLG_OFF + FLG_BYTES)

// ---------------------------------------------------------------------------
// prep: convert x to fp16 [t][b][k]; prepack weights into per-block MFMA
// fragment order; pack bias; zero flags and h fragment-buffer 0.
// W_pre frag index = ((bl*48 + kt)*2 + nt)*64 + lane ; elem e (k-fastest).
//   col c = nt*16 + (lane&15)  (c<8:f, <16:i, <24:o, <32:g), unit = c&7
//   k    = kt*32 + 8*(lane>>4) + e   (k<512 = x part, else h part)
// ---------------------------------------------------------------------------
__global__ void prep_kernel(const float* __restrict__ xin,
                            const float* __restrict__ wf, const float* __restrict__ wi,
                            const float* __restrict__ wo, const float* __restrict__ wc,
                            const float* __restrict__ bfp, const float* __restrict__ bip,
                            const float* __restrict__ bop, const float* __restrict__ bcp,
                            f16* __restrict__ x_h, f16x8* __restrict__ W_pre,
                            float* __restrict__ bias_pre, u32* __restrict__ flagz,
                            u32* __restrict__ hzero) {
  long long id = (long long)blockIdx.x * 256 + threadIdx.x;
  const long long NX = 16777216;  // 64*512*512
  const long long NW = 786432;    // 128*48*2*64 fragments
  const long long NB_ = 4096;     // 128*32 bias
  const long long NF = 65536;     // 512*128 flags
  const long long NH = 32768;     // h frag buffer 0 as u32 words (128 KB)
  if (id < NX) {
    int b = (int)(id >> 18);
    int t = (int)((id >> 9) & 511);
    int k = (int)(id & 511);
    x_h[(((long long)t * 64 + b) << 9) | k] = (f16)xin[id];
  } else if ((id -= NX) < NW) {
    int lane = (int)(id & 63);
    int nt = (int)((id >> 6) & 1);
    int ktbl = (int)(id >> 7);
    int kt = ktbl % 48;
    int bl = ktbl / 48;
    int c = nt * 16 + (lane & 15);
    int g = c >> 3;
    int j = bl * 8 + (c & 7);
    int kbase = kt * 32 + 8 * (lane >> 4);
    const float* src = (g == 0) ? wf : (g == 1) ? wi : (g == 2) ? wo : wc;
    const float* row = src + (long long)j * 1536 + kbase;
    f16x8 v;
#pragma unroll
    for (int e = 0; e < 8; ++e) v[e] = (f16)row[e];
    W_pre[id] = v;
  } else if ((id -= NW) < NB_) {
    int bl = (int)(id >> 5);
    int c = (int)(id & 31);
    int g = c >> 3;
    int j = bl * 8 + (c & 7);
    const float* src = (g == 0) ? bfp : (g == 1) ? bip : (g == 2) ? bop : bcp;
    bias_pre[id] = src[j];
  } else if ((id -= NB_) < NF) {
    flagz[id] = 0u;
  } else if ((id -= NF) < NH) {
    hzero[id] = 0u;
  }
}

// ---------------------------------------------------------------------------
__device__ __forceinline__ float sgm(float x) { return 1.0f / (1.0f + __expf(-x)); }
__device__ __forceinline__ float tnh(float x) { return 1.0f - 2.0f / (__expf(2.0f * x) + 1.0f); }

// 16B agent-scope (sc1) store: write-through to L3, coherent for remote XCDs
// after their acquire fence.
__device__ __forceinline__ void st16_sc1(f16x8* p, f16x8 v) {
  asm volatile("global_store_dwordx4 %0, %1, off sc1" : : "v"(p), "v"(v) : "memory");
}

// h fragment buffer layout (per 128 KB buffer):
//   f16x8 unit index = kt*256 + row*4 + lq   (kt<32, row<64, lq<4)
//   holds h[row][k] for k = kt*32 + lq*8 .. +8
__global__ __launch_bounds__(256, 1) void lstm_kernel(const f16* __restrict__ x_h,
                                                      const f16x8* __restrict__ W_pre,
                                                      const float* __restrict__ bias_pre,
                                                      f16x8* hfrag, float* hfinal, u32* flag) {
  __shared__ f16x8 Wlds[48 * 2 * 64];  // 96 KB
  __shared__ f16 hstage[64 * 8];       // 1 KB: block's h tile [row][unit]
  const int tid = threadIdx.x;
  const int bl = blockIdx.x;
  const int lane = tid & 63;
  const int wv = tid >> 6;  // 4 waves = 4 M-tiles of 16 batch rows

  {  // stage weight panel once
    const f16x8* src = W_pre + (long long)bl * (48 * 2 * 64);
    for (int i = tid; i < 48 * 2 * 64; i += 256) Wlds[i] = src[i];
  }
  __syncthreads();

  const int l15 = lane & 15;
  const int lq = lane >> 4;
  const int arow = 16 * wv + l15;           // A-fragment batch row
  const float bias0 = bias_pre[bl * 32 + l15];
  const float bias1 = bias_pre[bl * 32 + 16 + l15];
  const int jcol = bl * 8 + (lane & 7);     // owned hidden unit column
  const bool act = (l15 < 8);
  // writer address pieces (fragment layout): kt=bl>>2 const, lq-slot=bl&3 const
  const int wkt = bl >> 2;
  const int wlq = bl & 3;
  float cst0 = 0.f, cst1 = 0.f, cst2 = 0.f, cst3 = 0.f;  // fp32 cell state

  f32x4 xacc[2][2];  // [ntile][chain], x-part partial gates for next step

  auto xgemm = [&](int T) {
    f32x4 z = {0.f, 0.f, 0.f, 0.f};
    xacc[0][0] = z; xacc[0][1] = z; xacc[1][0] = z; xacc[1][1] = z;
    const f16* xr = x_h + (((long long)T * 64 + arow) << 9) + 8 * lq;
    f16x8 xf[16];
#pragma unroll
    for (int kk = 0; kk < 16; ++kk) xf[kk] = *(const f16x8*)(xr + kk * 32);
#pragma unroll
    for (int kk = 0; kk < 16; ++kk) {
      f16x8 b0 = Wlds[(kk * 2 + 0) * 64 + lane];
      f16x8 b1 = Wlds[(kk * 2 + 1) * 64 + lane];
      xacc[0][kk & 1] = __builtin_amdgcn_mfma_f32_16x16x32_f16(xf[kk], b0, xacc[0][kk & 1], 0, 0, 0);
      xacc[1][kk & 1] = __builtin_amdgcn_mfma_f32_16x16x32_f16(xf[kk], b1, xacc[1][kk & 1], 0, 0, 0);
    }
  };

  xgemm(0);  // prologue: x contribution for t=0

  for (int t = 0; t < SEQ; ++t) {
    const f16x8* hb = hfrag + (size_t)(t & 1) * 8192;       // read buffer
    f16x8* hwv_buf = hfrag + (size_t)((t + 1) & 1) * 8192;  // write buffer

    // make remote sc1 h-stores (step t-1) visible: invalidate L1/L2, then
    // CACHED loads -> 16 blocks/XCD share one L2 copy of the h buffer.
    __builtin_amdgcn_fence(__ATOMIC_ACQUIRE, "agent");

    f32x4 acc00 = xacc[0][0], acc01 = xacc[0][1];
    f32x4 acc10 = xacc[1][0], acc11 = xacc[1][1];

    // ---- h-GEMM: K=1024, 32 k-tiles; cached 16B fragment loads ----
    const f16x8* hb0 = hb + arow * 4 + lq;
    f16x8 hfr[32];
#pragma unroll
    for (int kt = 0; kt < 32; ++kt) hfr[kt] = hb0[kt * 256];
#pragma unroll
    for (int kt = 0; kt < 32; ++kt) {
      f16x8 b0 = Wlds[((16 + kt) * 2 + 0) * 64 + lane];
      f16x8 b1 = Wlds[((16 + kt) * 2 + 1) * 64 + lane];
      if (kt & 1) {
        acc01 = __builtin_amdgcn_mfma_f32_16x16x32_f16(hfr[kt], b0, acc01, 0, 0, 0);
        acc11 = __builtin_amdgcn_mfma_f32_16x16x32_f16(hfr[kt], b1, acc11, 0, 0, 0);
      } else {
        acc00 = __builtin_amdgcn_mfma_f32_16x16x32_f16(hfr[kt], b0, acc00, 0, 0, 0);
        acc10 = __builtin_amdgcn_mfma_f32_16x16x32_f16(hfr[kt], b1, acc10, 0, 0, 0);
      }
    }

    // ---- gates -> elementwise.  D layout: col=lane&15, row=(lane>>4)*4+r ----
    f32x4 g0 = acc00 + acc01;  // cols 0..15: f(0-7), i(8-15)
    f32x4 g1 = acc10 + acc11;  // cols 16..31: o(0-7), g(8-15)
#pragma unroll
    for (int r = 0; r < 4; ++r) { g0[r] += bias0; g1[r] += bias1; }

    float iv0 = __shfl_xor(g0[0], 8), iv1 = __shfl_xor(g0[1], 8);
    float iv2 = __shfl_xor(g0[2], 8), iv3 = __shfl_xor(g0[3], 8);
    float gv0 = __shfl_xor(g1[0], 8), gv1 = __shfl_xor(g1[1], 8);
    float gv2 = __shfl_xor(g1[2], 8), gv3 = __shfl_xor(g1[3], 8);

    if (act) {
      const int brb = 16 * wv + 4 * lq;
#pragma unroll
      for (int r = 0; r < 4; ++r) {
        float fpre = (r == 0) ? g0[0] : (r == 1) ? g0[1] : (r == 2) ? g0[2] : g0[3];
        float opre = (r == 0) ? g1[0] : (r == 1) ? g1[1] : (r == 2) ? g1[2] : g1[3];
        float ipre = (r == 0) ? iv0 : (r == 1) ? iv1 : (r == 2) ? iv2 : iv3;
        float gpre = (r == 0) ? gv0 : (r == 1) ? gv1 : (r == 2) ? gv2 : gv3;
        float cold = (r == 0) ? cst0 : (r == 1) ? cst1 : (r == 2) ? cst2 : cst3;
        float cn = sgm(fpre) * cold + sgm(ipre) * tnh(gpre);
        float hv = sgm(opre) * tnh(cn);
        if (r == 0) cst0 = cn; else if (r == 1) cst1 = cn; else if (r == 2) cst2 = cn; else cst3 = cn;
        int row = brb + r;
        hstage[row * 8 + l15] = (f16)hv;                 // LDS gather
        if (t == SEQ - 1) hfinal[row * 1024 + jcol] = hv;
      }
    }

    __syncthreads();  // hstage ready for wave0's gather
    if (t + 1 < SEQ) {
      // ---- wave0: 64 x 16B sc1 stores, drain, tid0 publishes flag ----
      // (flag is also the intra-block release: no wave passes the poll until
      //  its own block's flag is set, so hstage can't be overwritten early)
      if (tid < 64) {
        f16x8 hrow = *(const f16x8*)&hstage[tid * 8];
        st16_sc1(hwv_buf + (wkt * 256 + tid * 4 + wlq), hrow);
        asm volatile("s_waitcnt vmcnt(0)" ::: "memory");
        if (tid == 0)
          __hip_atomic_store(&flag[(size_t)t * NBLK + bl], 1u, __ATOMIC_RELAXED,
                             __HIP_MEMORY_SCOPE_AGENT);
      }
      // ---- overlap x-GEMM(t+1) with the wait; ALL waves poll ----
      xgemm(t + 1);
      {
        const u32* fl = flag + (size_t)t * NBLK;
        u32 it = 0;
        while (true) {
          u32 a = __hip_atomic_load(fl + 2 * lane, __ATOMIC_RELAXED, __HIP_MEMORY_SCOPE_AGENT);
          u32 b = __hip_atomic_load(fl + 2 * lane + 1, __ATOMIC_RELAXED, __HIP_MEMORY_SCOPE_AGENT);
          if (__all((a & b) == 1u)) break;  // all 128 flags set
          __builtin_amdgcn_s_sleep(1);
          if (++it > 50000u) break;  // hang guard: wrong answer beats a hang
        }
      }
    }
  }
}

// ---------------------------------------------------------------------------
__global__ void logits_kernel(const float* __restrict__ hfinal, const float* __restrict__ ow,
                              const float* __restrict__ ob, float* __restrict__ out) {
  int b = blockIdx.x / 10;
  int o = blockIdx.x % 10;
  int lane = threadIdx.x;
  const float* hrow = hfinal + b * 1024;
  const float* wrow = ow + o * 1024;
  float s = 0.f;
#pragma unroll 4
  for (int i = lane; i < 1024; i += 64) s += hrow[i] * wrow[i];
#pragma unroll
  for (int off = 32; off; off >>= 1) s += __shfl_xor(s, off);
  if (lane == 0) out[b * 10 + o] = s + ob[o];
}

// ---------------------------------------------------------------------------
extern "C" void kernel_launch(void* const* d_in, const int* in_sizes, int n_in,
                              void* d_out, int out_size, void* d_ws, size_t ws_size,
                              hipStream_t stream) {
  const float* xin = (const float*)d_in[0];
  const float* wf = (const float*)d_in[1];
  const float* bf = (const float*)d_in[2];
  const float* wi = (const float*)d_in[3];
  const float* bi = (const float*)d_in[4];
  const float* wo = (const float*)d_in[5];
  const float* bo = (const float*)d_in[6];
  const float* wc = (const float*)d_in[7];
  const float* bc = (const float*)d_in[8];
  const float* ow = (const float*)d_in[9];
  const float* ob = (const float*)d_in[10];
  (void)in_sizes; (void)n_in; (void)out_size;

  if (ws_size < WS_NEEDED) return;  // need ~47 MB scratch
  char* ws = (char*)d_ws;
  f16* x_h = (f16*)(ws + XH_OFF);
  f16x8* W_pre = (f16x8*)(ws + WPRE_OFF);
  float* bias_pre = (float*)(ws + BIAS_OFF);
  f16x8* hfrag = (f16x8*)(ws + HBUF_OFF);
  float* hfinal = (float*)(ws + HFIN_OFF);
  u32* flag = (u32*)(ws + FLG_OFF);

  const long long total = 16777216LL + 786432 + 4096 + 65536 + 32768;
  const int pblocks = (int)((total + 255) / 256);
  prep_kernel<<<pblocks, 256, 0, stream>>>(xin, wf, wi, wo, wc, bf, bi, bo, bc, x_h, W_pre,
                                           bias_pre, flag, (u32*)hfrag);
  lstm_kernel<<<NBLK, 256, 0, stream>>>(x_h, W_pre, bias_pre, hfrag, hfinal, flag);
  logits_kernel<<<640, 64, 0, stream>>>(hfinal, ow, ob, (float*)d_out);
}

// Round 7
// 3293.906 us; speedup vs baseline: 1.3633x; 1.3633x over previous
//
#include <hip/hip_runtime.h>

// CustomLSTMClassifier on MI355X (gfx950) — round 7
// Persistent 128-block kernel, 512 sequential LSTM steps.
// vs round 4 (best, 3956 us): 512 threads (8 waves = 2/SIMD for latency
// overlap), h-GEMM K-split across two wave-groups (16 sc1 loads/wave instead
// of 32), LDS partial-sum combine, wave0-only poll + syncthreads release.
// Communication layer identical to round 4: 16B sc1 loads/stores, no fence.

typedef _Float16 f16;
typedef _Float16 f16x8 __attribute__((ext_vector_type(8)));
typedef float f32x4 __attribute__((ext_vector_type(4)));
typedef unsigned short u16;
typedef unsigned int u32;

#define NBLK 128
#define SEQ 512

// workspace layout (bytes)
#define XH_OFF 0ull
#define XH_BYTES (64ull * 512 * 512 * 2)       // 33554432  x in fp16, [t][b][k]
#define WPRE_OFF (XH_OFF + XH_BYTES)
#define WPRE_BYTES (128ull * 48 * 2 * 64 * 16) // 12582912  per-block fragment-packed W
#define BIAS_OFF (WPRE_OFF + WPRE_BYTES)
#define BIAS_BYTES (128ull * 32 * 4)
#define HBUF_OFF (BIAS_OFF + BIAS_BYTES)
#define HBUF_BYTES (2ull * 32 * 64 * 4 * 16)   // 262144: dbuf h, frag order [kt][row][lq] x f16x8
#define HFIN_OFF (HBUF_OFF + HBUF_BYTES)
#define HFIN_BYTES (64ull * 1024 * 4)          // final h (fp32)
#define FLG_OFF (HFIN_OFF + HFIN_BYTES)
#define FLG_BYTES (512ull * 128 * 4)           // 262144: flag[t][bl]
#define WS_NEEDED (FLG_OFF + FLG_BYTES)

// ---------------------------------------------------------------------------
// prep: convert x to fp16 [t][b][k]; prepack weights into per-block MFMA
// fragment order; pack bias; zero flags and h fragment-buffer 0.
// W_pre frag index = ((bl*48 + kt)*2 + nt)*64 + lane ; elem e (k-fastest).
//   col c = nt*16 + (lane&15)  (c<8:f, <16:i, <24:o, <32:g), unit = c&7
//   k    = kt*32 + 8*(lane>>4) + e   (k<512 = x part, else h part)
// ---------------------------------------------------------------------------
__global__ void prep_kernel(const float* __restrict__ xin,
                            const float* __restrict__ wf, const float* __restrict__ wi,
                            const float* __restrict__ wo, const float* __restrict__ wc,
                            const float* __restrict__ bfp, const float* __restrict__ bip,
                            const float* __restrict__ bop, const float* __restrict__ bcp,
                            f16* __restrict__ x_h, f16x8* __restrict__ W_pre,
                            float* __restrict__ bias_pre, u32* __restrict__ flagz,
                            u32* __restrict__ hzero) {
  long long id = (long long)blockIdx.x * 256 + threadIdx.x;
  const long long NX = 16777216;  // 64*512*512
  const long long NW = 786432;    // 128*48*2*64 fragments
  const long long NB_ = 4096;     // 128*32 bias
  const long long NF = 65536;     // 512*128 flags
  const long long NH = 32768;     // h frag buffer 0 as u32 words (128 KB)
  if (id < NX) {
    int b = (int)(id >> 18);
    int t = (int)((id >> 9) & 511);
    int k = (int)(id & 511);
    x_h[(((long long)t * 64 + b) << 9) | k] = (f16)xin[id];
  } else if ((id -= NX) < NW) {
    int lane = (int)(id & 63);
    int nt = (int)((id >> 6) & 1);
    int ktbl = (int)(id >> 7);
    int kt = ktbl % 48;
    int bl = ktbl / 48;
    int c = nt * 16 + (lane & 15);
    int g = c >> 3;
    int j = bl * 8 + (c & 7);
    int kbase = kt * 32 + 8 * (lane >> 4);
    const float* src = (g == 0) ? wf : (g == 1) ? wi : (g == 2) ? wo : wc;
    const float* row = src + (long long)j * 1536 + kbase;
    f16x8 v;
#pragma unroll
    for (int e = 0; e < 8; ++e) v[e] = (f16)row[e];
    W_pre[id] = v;
  } else if ((id -= NW) < NB_) {
    int bl = (int)(id >> 5);
    int c = (int)(id & 31);
    int g = c >> 3;
    int j = bl * 8 + (c & 7);
    const float* src = (g == 0) ? bfp : (g == 1) ? bip : (g == 2) ? bop : bcp;
    bias_pre[id] = src[j];
  } else if ((id -= NB_) < NF) {
    flagz[id] = 0u;
  } else if ((id -= NF) < NH) {
    hzero[id] = 0u;
  }
}

// ---------------------------------------------------------------------------
__device__ __forceinline__ float sgm(float x) { return 1.0f / (1.0f + __expf(-x)); }
__device__ __forceinline__ float tnh(float x) { return 1.0f - 2.0f / (__expf(2.0f * x) + 1.0f); }

// 16B agent-scope (sc1) load/store: L2-bypass, coherent with sc1 write-through.
__device__ __forceinline__ void ld16_sc1(f16x8* dst, const f16x8* p) {
  asm volatile("global_load_dwordx4 %0, %1, off sc1" : "=v"(*dst) : "v"(p) : "memory");
}
__device__ __forceinline__ void st16_sc1(f16x8* p, f16x8 v) {
  asm volatile("global_store_dwordx4 %0, %1, off sc1" : : "v"(p), "v"(v) : "memory");
}

// h fragment buffer layout (per 128 KB buffer):
//   f16x8 unit index = kt*256 + row*4 + lq   (kt<32, row<64, lq<4)
//   holds h[row][k] for k = kt*32 + lq*8 .. +8
__global__ __launch_bounds__(512, 1) void lstm_kernel(const f16* __restrict__ x_h,
                                                      const f16x8* __restrict__ W_pre,
                                                      const float* __restrict__ bias_pre,
                                                      f16x8* hfrag, float* hfinal, u32* flag) {
  __shared__ f16x8 Wlds[48 * 2 * 64];  // 96 KB
  __shared__ f32x4 comb[4 * 64 * 2];   // 8 KB: group-B partial gates [mwv][lane][nt]
  __shared__ f16 hstage[64 * 8];       // 1 KB: block's h tile [row][unit]
  const int tid = threadIdx.x;
  const int bl = blockIdx.x;
  const int lane = tid & 63;
  const int wv = tid >> 6;   // 0..7
  const int grp = wv >> 2;   // 0: even k-tiles, 1: odd k-tiles
  const int mwv = wv & 3;    // m-tile (16 batch rows)

  {  // stage weight panel once
    const f16x8* src = W_pre + (long long)bl * (48 * 2 * 64);
    for (int i = tid; i < 48 * 2 * 64; i += 512) Wlds[i] = src[i];
  }
  __syncthreads();

  const int l15 = lane & 15;
  const int lq = lane >> 4;
  const int arow = 16 * mwv + l15;          // A-fragment batch row
  const float bias0 = bias_pre[bl * 32 + l15];
  const float bias1 = bias_pre[bl * 32 + 16 + l15];
  const int jcol = bl * 8 + (lane & 7);     // owned hidden unit column
  const bool act = (l15 < 8);
  // writer address pieces (fragment layout): kt=bl>>2 const, lq-slot=bl&3 const
  const int wkt = bl >> 2;
  const int wlq = bl & 3;
  float cst0 = 0.f, cst1 = 0.f, cst2 = 0.f, cst3 = 0.f;  // fp32 cell state

  f32x4 xacc[2][2];  // [ntile][chain], this wave's x-part partials (its k-slice)

  auto xgemm = [&](int T) {
    f32x4 z = {0.f, 0.f, 0.f, 0.f};
    xacc[0][0] = z; xacc[0][1] = z; xacc[1][0] = z; xacc[1][1] = z;
    const f16* xr = x_h + (((long long)T * 64 + arow) << 9) + 8 * lq;
    f16x8 xf[8];
#pragma unroll
    for (int j = 0; j < 8; ++j) xf[j] = *(const f16x8*)(xr + (2 * j + grp) * 32);
#pragma unroll
    for (int j = 0; j < 8; ++j) {
      int kk = 2 * j + grp;
      f16x8 b0 = Wlds[(kk * 2 + 0) * 64 + lane];
      f16x8 b1 = Wlds[(kk * 2 + 1) * 64 + lane];
      xacc[0][j & 1] = __builtin_amdgcn_mfma_f32_16x16x32_f16(xf[j], b0, xacc[0][j & 1], 0, 0, 0);
      xacc[1][j & 1] = __builtin_amdgcn_mfma_f32_16x16x32_f16(xf[j], b1, xacc[1][j & 1], 0, 0, 0);
    }
  };

  xgemm(0);  // prologue: x contribution for t=0 (this wave's k-slice)

  for (int t = 0; t < SEQ; ++t) {
    const f16x8* hb = hfrag + (size_t)(t & 1) * 8192;       // read buffer
    f16x8* hwv_buf = hfrag + (size_t)((t + 1) & 1) * 8192;  // write buffer

    f32x4 acc00 = xacc[0][0], acc01 = xacc[0][1];
    f32x4 acc10 = xacc[1][0], acc11 = xacc[1][1];

    // ---- h-GEMM: this wave's 16 of 32 k-tiles; 16B sc1 fragment loads ----
    const f16x8* hb0 = hb + arow * 4 + lq;
    f16x8 hfr[16];
#pragma unroll
    for (int j = 0; j < 16; ++j) ld16_sc1(&hfr[j], hb0 + (2 * j + grp) * 256);
    asm volatile("s_waitcnt vmcnt(0)" ::: "memory");
    __builtin_amdgcn_sched_barrier(0);
#pragma unroll
    for (int j = 0; j < 16; ++j) {
      int kt = 2 * j + grp;
      f16x8 b0 = Wlds[((16 + kt) * 2 + 0) * 64 + lane];
      f16x8 b1 = Wlds[((16 + kt) * 2 + 1) * 64 + lane];
      if (j & 1) {
        acc01 = __builtin_amdgcn_mfma_f32_16x16x32_f16(hfr[j], b0, acc01, 0, 0, 0);
        acc11 = __builtin_amdgcn_mfma_f32_16x16x32_f16(hfr[j], b1, acc11, 0, 0, 0);
      } else {
        acc00 = __builtin_amdgcn_mfma_f32_16x16x32_f16(hfr[j], b0, acc00, 0, 0, 0);
        acc10 = __builtin_amdgcn_mfma_f32_16x16x32_f16(hfr[j], b1, acc10, 0, 0, 0);
      }
    }

    // ---- combine the two wave-groups' partials through LDS ----
    f32x4 p0 = acc00 + acc01;  // cols 0..15: f(0-7), i(8-15)
    f32x4 p1 = acc10 + acc11;  // cols 16..31: o(0-7), g(8-15)
    if (grp == 1) {
      comb[(mwv * 64 + lane) * 2 + 0] = p0;
      comb[(mwv * 64 + lane) * 2 + 1] = p1;
    }
    __syncthreads();  // S1: partials ready

    if (grp == 0) {
      // ---- gates -> elementwise.  D layout: col=lane&15, row=(lane>>4)*4+r
      f32x4 g0 = p0 + comb[(mwv * 64 + lane) * 2 + 0];
      f32x4 g1 = p1 + comb[(mwv * 64 + lane) * 2 + 1];
#pragma unroll
      for (int r = 0; r < 4; ++r) { g0[r] += bias0; g1[r] += bias1; }

      float iv0 = __shfl_xor(g0[0], 8), iv1 = __shfl_xor(g0[1], 8);
      float iv2 = __shfl_xor(g0[2], 8), iv3 = __shfl_xor(g0[3], 8);
      float gv0 = __shfl_xor(g1[0], 8), gv1 = __shfl_xor(g1[1], 8);
      float gv2 = __shfl_xor(g1[2], 8), gv3 = __shfl_xor(g1[3], 8);

      if (act) {
        const int brb = 16 * mwv + 4 * lq;
#pragma unroll
        for (int r = 0; r < 4; ++r) {
          float fpre = (r == 0) ? g0[0] : (r == 1) ? g0[1] : (r == 2) ? g0[2] : g0[3];
          float opre = (r == 0) ? g1[0] : (r == 1) ? g1[1] : (r == 2) ? g1[2] : g1[3];
          float ipre = (r == 0) ? iv0 : (r == 1) ? iv1 : (r == 2) ? iv2 : iv3;
          float gpre = (r == 0) ? gv0 : (r == 1) ? gv1 : (r == 2) ? gv2 : gv3;
          float cold = (r == 0) ? cst0 : (r == 1) ? cst1 : (r == 2) ? cst2 : cst3;
          float cn = sgm(fpre) * cold + sgm(ipre) * tnh(gpre);
          float hv = sgm(opre) * tnh(cn);
          if (r == 0) cst0 = cn; else if (r == 1) cst1 = cn; else if (r == 2) cst2 = cn; else cst3 = cn;
          int row = brb + r;
          hstage[row * 8 + l15] = (f16)hv;                 // LDS gather
          if (t == SEQ - 1) hfinal[row * 1024 + jcol] = hv;
        }
      }
    }

    __syncthreads();  // S2: hstage ready; comb consumed
    if (t + 1 < SEQ) {
      // ---- wave0: 64 x 16B sc1 stores, drain, tid0 publishes flag ----
      if (tid < 64) {
        f16x8 hrow = *(const f16x8*)&hstage[tid * 8];
        st16_sc1(hwv_buf + (wkt * 256 + tid * 4 + wlq), hrow);
        asm volatile("s_waitcnt vmcnt(0)" ::: "memory");
        if (tid == 0)
          __hip_atomic_store(&flag[(size_t)t * NBLK + bl], 1u, __ATOMIC_RELAXED,
                             __HIP_MEMORY_SCOPE_AGENT);
      }
      // ---- overlap x-GEMM(t+1) with the wait; wave0 polls, then releases ----
      xgemm(t + 1);
      if (wv == 0) {
        const u32* fl = flag + (size_t)t * NBLK;
        u32 it = 0;
        while (true) {
          u32 a = __hip_atomic_load(fl + 2 * lane, __ATOMIC_RELAXED, __HIP_MEMORY_SCOPE_AGENT);
          u32 b = __hip_atomic_load(fl + 2 * lane + 1, __ATOMIC_RELAXED, __HIP_MEMORY_SCOPE_AGENT);
          if (__all((a & b) == 1u)) break;  // all 128 flags set
          __builtin_amdgcn_s_sleep(1);
          if (++it > 50000u) break;  // hang guard: wrong answer beats a hang
        }
      }
      __syncthreads();  // S3: release all waves into step t+1
    }
  }
}

// ---------------------------------------------------------------------------
__global__ void logits_kernel(const float* __restrict__ hfinal, const float* __restrict__ ow,
                              const float* __restrict__ ob, float* __restrict__ out) {
  int b = blockIdx.x / 10;
  int o = blockIdx.x % 10;
  int lane = threadIdx.x;
  const float* hrow = hfinal + b * 1024;
  const float* wrow = ow + o * 1024;
  float s = 0.f;
#pragma unroll 4
  for (int i = lane; i < 1024; i += 64) s += hrow[i] * wrow[i];
#pragma unroll
  for (int off = 32; off; off >>= 1) s += __shfl_xor(s, off);
  if (lane == 0) out[b * 10 + o] = s + ob[o];
}

// ---------------------------------------------------------------------------
extern "C" void kernel_launch(void* const* d_in, const int* in_sizes, int n_in,
                              void* d_out, int out_size, void* d_ws, size_t ws_size,
                              hipStream_t stream) {
  const float* xin = (const float*)d_in[0];
  const float* wf = (const float*)d_in[1];
  const float* bf = (const float*)d_in[2];
  const float* wi = (const float*)d_in[3];
  const float* bi = (const float*)d_in[4];
  const float* wo = (const float*)d_in[5];
  const float* bo = (const float*)d_in[6];
  const float* wc = (const float*)d_in[7];
  const float* bc = (const float*)d_in[8];
  const float* ow = (const float*)d_in[9];
  const float* ob = (const float*)d_in[10];
  (void)in_sizes; (void)n_in; (void)out_size;

  if (ws_size < WS_NEEDED) return;  // need ~47 MB scratch
  char* ws = (char*)d_ws;
  f16* x_h = (f16*)(ws + XH_OFF);
  f16x8* W_pre = (f16x8*)(ws + WPRE_OFF);
  float* bias_pre = (float*)(ws + BIAS_OFF);
  f16x8* hfrag = (f16x8*)(ws + HBUF_OFF);
  float* hfinal = (float*)(ws + HFIN_OFF);
  u32* flag = (u32*)(ws + FLG_OFF);

  const long long total = 16777216LL + 786432 + 4096 + 65536 + 32768;
  const int pblocks = (int)((total + 255) / 256);
  prep_kernel<<<pblocks, 256, 0, stream>>>(xin, wf, wi, wo, wc, bf, bi, bo, bc, x_h, W_pre,
                                           bias_pre, flag, (u32*)hfrag);
  lstm_kernel<<<NBLK, 512, 0, stream>>>(x_h, W_pre, bias_pre, hfrag, hfinal, flag);
  logits_kernel<<<640, 64, 0, stream>>>(hfinal, ow, ob, (float*)d_out);
}